// Round 8
// baseline (452.901 us; speedup 1.0000x reference)
//
#include <hip/hip_runtime.h>
#include <hip/hip_bf16.h>

typedef unsigned short u16;
typedef __attribute__((ext_vector_type(8))) short bf16x8;
typedef __attribute__((ext_vector_type(4))) float f32x4;
typedef __attribute__((ext_vector_type(4))) unsigned short u16x4;
typedef __attribute__((ext_vector_type(4))) unsigned int u32x4;

// raw RNE fp32->bf16 (no NaN handling -- all values in this pipeline are finite)
__device__ __forceinline__ u16 f2b(float f) {
    unsigned u = __float_as_uint(f);
    u += 0x7fffu + ((u >> 16) & 1u);
    return (u16)(u >> 16);
}
__device__ __forceinline__ float bf2f(u16 u) {
    return __uint_as_float(((unsigned)u) << 16);
}
// async global->LDS, 16B per lane; dest = wave-uniform base + lane*16 (HW)
__device__ __forceinline__ void gload16(const void* g, void* l) {
    __builtin_amdgcn_global_load_lds(
        (const __attribute__((address_space(1))) unsigned int*)g,
        (__attribute__((address_space(3))) unsigned int*)l, 16, 0, 0);
}

// ---------------- fp32 -> bf16 bulk convert (8 elems/thread) --------------------
__global__ __launch_bounds__(256)
void cvt_kernel(const float* __restrict__ in, u16* __restrict__ out) {
    size_t i = ((size_t)blockIdx.x * 256 + threadIdx.x) * 8;
    f32x4 a = *(const f32x4*)(in + i);
    f32x4 b = *(const f32x4*)(in + i + 4);
    u16x4 p0 = { f2b(a[0]), f2b(a[1]), f2b(a[2]), f2b(a[3]) };
    u16x4 p1 = { f2b(b[0]), f2b(b[1]), f2b(b[2]), f2b(b[3]) };
    *(u16x4*)(out + i) = p0;
    *(u16x4*)(out + i + 4) = p1;
}

// ---------------- weight transpose + convert: Wt[n][k] = bf16(W[k][n]) ----------
__global__ __launch_bounds__(256)
void wt_kernel(const float* __restrict__ Wq, const float* __restrict__ Wk,
               const float* __restrict__ Wv, const float* __restrict__ Wo,
               u16* __restrict__ Wt) {
    const float* W = blockIdx.z == 0 ? Wq : blockIdx.z == 1 ? Wk : blockIdx.z == 2 ? Wv : Wo;
    u16* Out = Wt + (size_t)blockIdx.z * (1024 * 1024);
    __shared__ float T[64][65];
    const int t = threadIdx.x;
    const int r0 = blockIdx.y * 64, c0 = blockIdx.x * 64;
#pragma unroll
    for (int e = 0; e < 4; ++e) {
        int row = e * 16 + (t >> 4), c4 = (t & 15) * 4;
        f32x4 v = *(const f32x4*)(W + (r0 + row) * 1024 + c0 + c4);
        T[row][c4] = v[0]; T[row][c4 + 1] = v[1]; T[row][c4 + 2] = v[2]; T[row][c4 + 3] = v[3];
    }
    __syncthreads();
#pragma unroll
    for (int e = 0; e < 4; ++e) {
        int orow = e * 16 + (t >> 4), oc4 = (t & 15) * 4;
        u16x4 pk = { f2b(T[oc4][orow]), f2b(T[oc4 + 1][orow]),
                     f2b(T[oc4 + 2][orow]), f2b(T[oc4 + 3][orow]) };
        *(u16x4*)(Out + (c0 + orow) * 1024 + r0 + oc4) = pk;
    }
}

// ---------------- GEMM v2: no LDS, direct L2 fragment loads ---------------------
// Each wave owns a 64x64 output tile; A/B fragments for 16x16x32 are 16B rows ->
// one global_load_dwordx4 each. No barriers; compiler pipelines loads vs MFMA.
// Grid (64,8): blocks sharing an A-panel (same bIdx.x) are id==bx (mod 8) -> same
// XCD -> A fetched from HBM once; B dup x8 = 17MB (trivial).
template <int BIAS>
__global__ __launch_bounds__(256)
void gemm_kernel(const u16* __restrict__ Ab, const u16* __restrict__ Bt,
                 u16* __restrict__ Cb, float* __restrict__ Cf,
                 const float* __restrict__ bias) {
    constexpr int K = 1024;
    const int tid = threadIdx.x;
    const int lane = tid & 63, w = tid >> 6;
    const int c = lane & 15, g = lane >> 4;
    const int m0 = blockIdx.x * 128 + (w >> 1) * 64;
    const int n0 = blockIdx.y * 128 + (w & 1) * 64;
    const u16* aB = Ab + (size_t)(m0 + c) * K + 8 * g;
    const u16* bB = Bt + (size_t)(n0 + c) * K + 8 * g;
    f32x4 acc[4][4] = {};
    for (int kt = 0; kt < 16; ++kt) {
        const int k0 = kt * 64;
        bf16x8 af[2][4], bfr[2][4];
#pragma unroll
        for (int kk = 0; kk < 2; ++kk)
#pragma unroll
            for (int m = 0; m < 4; ++m) {
                af[kk][m]  = *(const bf16x8*)(aB + (size_t)m * 16 * K + k0 + kk * 32);
                bfr[kk][m] = *(const bf16x8*)(bB + (size_t)m * 16 * K + k0 + kk * 32);
            }
#pragma unroll
        for (int kk = 0; kk < 2; ++kk)
#pragma unroll
            for (int m = 0; m < 4; ++m)
#pragma unroll
                for (int n = 0; n < 4; ++n)
                    acc[m][n] = __builtin_amdgcn_mfma_f32_16x16x32_bf16(af[kk][m], bfr[kk][n], acc[m][n], 0, 0, 0);
    }
#pragma unroll
    for (int n = 0; n < 4; ++n) {
        int col = n0 + n * 16 + c;
        float bv = BIAS ? bias[col] : 0.0f;
#pragma unroll
        for (int m = 0; m < 4; ++m) {
            int row0 = m0 + m * 16 + 4 * g;
#pragma unroll
            for (int r = 0; r < 4; ++r) {
                if (BIAS) Cf[(row0 + r) * 1024 + col] = acc[m][n][r] + bv;
                else      Cb[(row0 + r) * 1024 + col] = f2b(acc[m][n][r]);
            }
        }
    }
}

// ---------------- LayerNorm over D=1024 (bf16 in), write bf16 [bh][s][hd] -------
__global__ __launch_bounds__(256)
void ln_kernel(const u16* __restrict__ P, const float* __restrict__ gamma,
               const float* __restrict__ beta, float mul, u16* __restrict__ Out) {
    const int row = blockIdx.x;
    const int tid = threadIdx.x;
    const int lane = tid & 63, w = tid >> 6;
    u16x4 xr = *(const u16x4*)(P + row * 1024 + tid * 4);
    float x0 = bf2f(xr[0]), x1 = bf2f(xr[1]), x2 = bf2f(xr[2]), x3 = bf2f(xr[3]);
    float s = x0 + x1 + x2 + x3;
    float sq = x0 * x0 + x1 * x1 + x2 * x2 + x3 * x3;
#pragma unroll
    for (int m = 1; m < 64; m <<= 1) { s += __shfl_xor(s, m); sq += __shfl_xor(sq, m); }
    __shared__ float red[8];
    if (lane == 0) { red[w] = s; red[4 + w] = sq; }
    __syncthreads();
    float st = red[0] + red[1] + red[2] + red[3];
    float sqt = red[4] + red[5] + red[6] + red[7];
    float mu = st * (1.0f / 1024.0f);
    float var = sqt * (1.0f / 1024.0f) - mu * mu;
    float rs = rsqrtf(var + 1e-5f);
    f32x4 gm = *(const f32x4*)(gamma + tid * 4);
    f32x4 bt = *(const f32x4*)(beta + tid * 4);
    float xs[4] = {x0, x1, x2, x3};
    u16x4 pk;
#pragma unroll
    for (int j = 0; j < 4; ++j)
        pk[j] = f2b(((xs[j] - mu) * rs * gm[j] + bt[j]) * mul);
    const int b = row >> 11, sI = row & 2047;
    const int col = tid * 4, hh = col >> 6, d = col & 63;
    *(u16x4*)(Out + (((b * 16 + hh) * 2048 + sI) << 6) + d) = pk;
}

// ---------------- V transpose: Vt[bh][64][S] (bf16 in/out) ----------------------
__global__ __launch_bounds__(256)
void vt_kernel(const u16* __restrict__ P, u16* __restrict__ Vt) {
    __shared__ u16 T[64][72];
    const int t = threadIdx.x;
    const int bh = blockIdx.y, s0 = blockIdx.x * 64;
    const int b = bh >> 4, h = bh & 15;
#pragma unroll
    for (int e = 0; e < 4; ++e) {
        int row = e * 16 + (t >> 4), c4 = (t & 15) * 4;
        u16x4 v = *(const u16x4*)(P + (b * 2048 + s0 + row) * 1024 + h * 64 + c4);
        *(u16x4*)&T[row][c4] = v;
    }
    __syncthreads();
#pragma unroll
    for (int e = 0; e < 4; ++e) {
        int dd = e * 16 + (t >> 4), s4 = (t & 15) * 4;
        u16x4 pk = { T[s4][dd], T[s4 + 1][dd], T[s4 + 2][dd], T[s4 + 3][dd] };
        *(u16x4*)(Vt + ((size_t)bh * 64 + dd) * 2048 + s0 + s4) = pk;
    }
}

// ---------------- flash attention v5: no-max softmax, DMA staging ---------------
__global__ __launch_bounds__(256)
void attn_kernel(const u16* __restrict__ Qa, const u16* __restrict__ Ka,
                 const u16* __restrict__ Vt, u16* __restrict__ Xa) {
    __shared__ u16 Ks[2][4096];   // 8KB each: [64][64] swizzled
    __shared__ u16 Vs[2][4096];   // 8KB each: [64][64] swizzled (rows = d)
    __shared__ u16 Pl[4][1024];   // 2KB/wave: [16 q][64 k] swizzled
    const int tid = threadIdx.x;
    const int lane = tid & 63, w = tid >> 6;
    const int c = lane & 15, g = lane >> 4;
    const int bid = blockIdx.x;
    const int bh = (bid & 7) * 8 + ((bid >> 3) & 7);
    const int q0 = (bid >> 6) * 64;
    const int b = bh >> 4, h = bh & 15;

    const int qrow = q0 + w * 16 + c;
    const u16* qptr = Qa + ((size_t)bh * 2048 + qrow) * 64;
    bf16x8 qf0 = *(const bf16x8*)(qptr + 8 * g);
    bf16x8 qf1 = *(const bf16x8*)(qptr + 32 + 8 * g);

    const int sr = lane >> 3;
    const int scg = ((lane & 7) ^ sr) * 8;
    const u16* kA = Ka + ((size_t)bh * 2048 + sr) * 64 + scg;
    const u16* vA = Vt + ((size_t)bh * 64 + sr) * 2048 + scg;
    const int pswz = (c & 7) << 4;

    f32x4 o[4] = {};
    float li = 0.f;
    char* pb = (char*)&Pl[w][0];

    // prologue: stage tile 0 into buf 0
#pragma unroll
    for (int j = 0; j < 2; ++j) {
        const int m = 2 * w + j;
        gload16(kA + (size_t)(8 * m) * 64, &Ks[0][8 * m * 64]);
        gload16(vA + (size_t)(8 * m) * 2048, &Vs[0][8 * m * 64]);
    }
    __syncthreads();

    int cur = 0;
#pragma unroll 2
    for (int t = 0; t < 32; ++t) {
        // issue async staging of next tile into the other buffer
        const int tn = (t + 1) & 31;
#pragma unroll
        for (int j = 0; j < 2; ++j) {
            const int m = 2 * w + j;
            gload16(kA + (size_t)(tn * 64 + 8 * m) * 64, &Ks[cur ^ 1][8 * m * 64]);
            gload16(vA + (size_t)(8 * m) * 2048 + tn * 64, &Vs[cur ^ 1][8 * m * 64]);
        }

        // QK^T (swapped): sacc[ct][r] = S[k=16ct+4g+r][q=c]
        const char* kbase = (const char*)&Ks[cur][0];
        f32x4 sacc[4] = {};
        __builtin_amdgcn_s_setprio(1);
#pragma unroll
        for (int ct = 0; ct < 4; ++ct) {
            const int rb = (c + 16 * ct) * 128;
            bf16x8 kf0 = *(const bf16x8*)(kbase + rb + ((16 * g) ^ pswz));
            bf16x8 kf1 = *(const bf16x8*)(kbase + rb + ((64 + 16 * g) ^ pswz));
            sacc[ct] = __builtin_amdgcn_mfma_f32_16x16x32_bf16(kf0, qf0, sacc[ct], 0, 0, 0);
            sacc[ct] = __builtin_amdgcn_mfma_f32_16x16x32_bf16(kf1, qf1, sacc[ct], 0, 0, 0);
        }
        __builtin_amdgcn_s_setprio(0);

        // P = exp2(S) directly (no max shift); lane-partial sum into li
#pragma unroll
        for (int ct = 0; ct < 4; ++ct) {
            float e0 = exp2f(sacc[ct][0]);
            float e1 = exp2f(sacc[ct][1]);
            float e2 = exp2f(sacc[ct][2]);
            float e3 = exp2f(sacc[ct][3]);
            li += (e0 + e1) + (e2 + e3);
            u16x4 pk = { f2b(e0), f2b(e1), f2b(e2), f2b(e3) };
            *(u16x4*)(pb + 128 * c + ((32 * ct + 8 * g) ^ pswz)) = pk;
        }

        // PV from Pl (wave-private) and Vs[cur]
        const char* vb = (const char*)&Vs[cur][0];
        __builtin_amdgcn_s_setprio(1);
#pragma unroll
        for (int s4 = 0; s4 < 2; ++s4) {
            const int co = ((64 * s4 + 16 * g) ^ pswz);
            bf16x8 af = *(const bf16x8*)(pb + 128 * c + co);
#pragma unroll
            for (int n = 0; n < 4; ++n) {
                bf16x8 vf = *(const bf16x8*)(vb + (c + 16 * n) * 128 + co);
                o[n] = __builtin_amdgcn_mfma_f32_16x16x32_bf16(af, vf, o[n], 0, 0, 0);
            }
        }
        __builtin_amdgcn_s_setprio(0);

        __syncthreads();   // next tile staged + all reads of cur done
        cur ^= 1;
    }

    // reduce li across the 4 g-groups once, then normalize
    li += __shfl_xor(li, 16);
    li += __shfl_xor(li, 32);
    float inv = 1.0f / li;
    float i0 = __shfl(inv, 4 * g + 0);
    float i1 = __shfl(inv, 4 * g + 1);
    float i2 = __shfl(inv, 4 * g + 2);
    float i3 = __shfl(inv, 4 * g + 3);
    float iv[4] = {i0, i1, i2, i3};
#pragma unroll
    for (int r = 0; r < 4; ++r) {
        int row = q0 + w * 16 + 4 * g + r;
        u16* xp = Xa + ((size_t)b * 2048 + row) * 1024 + h * 64;
#pragma unroll
        for (int n = 0; n < 4; ++n)
            xp[n * 16 + c] = f2b(o[n][r] * iv[r]);
    }
}

// ---------------- launch --------------------------------------------------------
extern "C" void kernel_launch(void* const* d_in, const int* in_sizes, int n_in,
                              void* d_out, int out_size, void* d_ws, size_t ws_size,
                              hipStream_t stream) {
    const float* q   = (const float*)d_in[0];
    const float* k   = (const float*)d_in[1];
    const float* v   = (const float*)d_in[2];
    const float* Wq  = (const float*)d_in[3];
    const float* Wk  = (const float*)d_in[4];
    const float* Wv  = (const float*)d_in[5];
    const float* Wo  = (const float*)d_in[6];
    const float* bo  = (const float*)d_in[7];
    const float* qg  = (const float*)d_in[8];
    const float* qbt = (const float*)d_in[9];
    const float* kg  = (const float*)d_in[10];
    const float* kbt = (const float*)d_in[11];

    char* ws = (char*)d_ws;
    u16* Wt = (u16*)(ws);                    //  8,388,608 B
    u16* Pb = (u16*)(ws + 8388608);          // 16,777,216 B
    u16* Qa = (u16*)(ws + 25165824);         // 16,777,216 B
    u16* Ka = (u16*)(ws + 41943040);         // 16,777,216 B
    u16* Vt = (u16*)(ws + 58720256);         // 16,777,216 B
    u16* Ib = (u16*)(ws + 75497472);         // 16,777,216 B bf16 input slot (end 92MB)
    u16* Xa = Pb;                            // reuse: P dead after vt_kernel

    const float MUL_Q = 0.04508422002778f;   // (1/32) * log2(e)

    wt_kernel<<<dim3(16, 16, 4), 256, 0, stream>>>(Wq, Wk, Wv, Wo, Wt);

    cvt_kernel<<<4096, 256, 0, stream>>>(q, Ib);
    gemm_kernel<0><<<dim3(64, 8), 256, 0, stream>>>(Ib, Wt, Pb, nullptr, nullptr);
    ln_kernel<<<8192, 256, 0, stream>>>(Pb, qg, qbt, MUL_Q, Qa);

    cvt_kernel<<<4096, 256, 0, stream>>>(k, Ib);
    gemm_kernel<0><<<dim3(64, 8), 256, 0, stream>>>(Ib, Wt + 1048576, Pb, nullptr, nullptr);
    ln_kernel<<<8192, 256, 0, stream>>>(Pb, kg, kbt, 1.0f, Ka);

    cvt_kernel<<<4096, 256, 0, stream>>>(v, Ib);
    gemm_kernel<0><<<dim3(64, 8), 256, 0, stream>>>(Ib, Wt + 2097152, Pb, nullptr, nullptr);
    vt_kernel<<<dim3(32, 64), 256, 0, stream>>>(Pb, Vt);

    attn_kernel<<<2048, 256, 0, stream>>>(Qa, Ka, Vt, Xa);

    gemm_kernel<1><<<dim3(64, 8), 256, 0, stream>>>((const u16*)Xa, Wt + 3145728, nullptr, (float*)d_out, bo);
}

// Round 9
// 329.497 us; speedup vs baseline: 1.3745x; 1.3745x over previous
//
#include <hip/hip_runtime.h>
#include <hip/hip_bf16.h>

typedef unsigned short u16;
typedef __attribute__((ext_vector_type(8))) short bf16x8;
typedef __attribute__((ext_vector_type(4))) float f32x4;
typedef __attribute__((ext_vector_type(4))) unsigned short u16x4;
typedef __attribute__((ext_vector_type(4))) unsigned int u32x4;

__device__ __forceinline__ u16 f2b(float f) {
    __hip_bfloat16 h = __float2bfloat16(f);
    u16 r; __builtin_memcpy(&r, &h, 2); return r;
}
__device__ __forceinline__ float bf2f(u16 u) {
    return __uint_as_float(((unsigned)u) << 16);
}
// async global->LDS, 16B per lane; dest = wave-uniform base + lane*16 (HW)
__device__ __forceinline__ void gload16(const void* g, void* l) {
    __builtin_amdgcn_global_load_lds(
        (const __attribute__((address_space(1))) unsigned int*)g,
        (__attribute__((address_space(3))) unsigned int*)l, 16, 0, 0);
}

// ---------------- fp32 -> bf16 bulk convert (8 elems/thread) --------------------
__global__ __launch_bounds__(256)
void cvt_kernel(const float* __restrict__ in, u16* __restrict__ out) {
    size_t i = ((size_t)blockIdx.x * 256 + threadIdx.x) * 8;
    f32x4 a = *(const f32x4*)(in + i);
    f32x4 b = *(const f32x4*)(in + i + 4);
    u16x4 p0 = { f2b(a[0]), f2b(a[1]), f2b(a[2]), f2b(a[3]) };
    u16x4 p1 = { f2b(b[0]), f2b(b[1]), f2b(b[2]), f2b(b[3]) };
    *(u16x4*)(out + i) = p0;
    *(u16x4*)(out + i + 4) = p1;
}

// ---------------- weight transpose + convert: Wt[n][k] = bf16(W[k][n]) ----------
__global__ __launch_bounds__(256)
void wt_kernel(const float* __restrict__ Wq, const float* __restrict__ Wk,
               const float* __restrict__ Wv, const float* __restrict__ Wo,
               u16* __restrict__ Wt) {
    const float* W = blockIdx.z == 0 ? Wq : blockIdx.z == 1 ? Wk : blockIdx.z == 2 ? Wv : Wo;
    u16* Out = Wt + (size_t)blockIdx.z * (1024 * 1024);
    __shared__ float T[64][65];
    const int t = threadIdx.x;
    const int r0 = blockIdx.y * 64, c0 = blockIdx.x * 64;
#pragma unroll
    for (int e = 0; e < 4; ++e) {
        int row = e * 16 + (t >> 4), c4 = (t & 15) * 4;
        f32x4 v = *(const f32x4*)(W + (r0 + row) * 1024 + c0 + c4);
        T[row][c4] = v[0]; T[row][c4 + 1] = v[1]; T[row][c4 + 2] = v[2]; T[row][c4 + 3] = v[3];
    }
    __syncthreads();
#pragma unroll
    for (int e = 0; e < 4; ++e) {
        int orow = e * 16 + (t >> 4), oc4 = (t & 15) * 4;
        u16x4 pk = { f2b(T[oc4][orow]), f2b(T[oc4 + 1][orow]),
                     f2b(T[oc4 + 2][orow]), f2b(T[oc4 + 3][orow]) };
        *(u16x4*)(Out + (c0 + orow) * 1024 + r0 + oc4) = pk;
    }
}

// ---------------- GEMM v3: LDS double-buffered 2-phase (gload16 DMA) ------------
// Per K-tile: issue next tile's global_load_lds into buf^1, compute current buf,
// ONE barrier (drains DMA + read-fence). 64KB LDS, 2 blocks/CU.
template <int BIAS>
__global__ __launch_bounds__(256)
void gemm_kernel(const u16* __restrict__ Ab, const u16* __restrict__ Bt,
                 u16* __restrict__ Cb, float* __restrict__ Cf,
                 const float* __restrict__ bias) {
    constexpr int K = 1024;
    __shared__ u16 As[2][8192];
    __shared__ u16 Bs[2][8192];
    const int tid = threadIdx.x;
    const int lane = tid & 63, w = tid >> 6;
    const int wr = w >> 1, wc = w & 1;
    const int c = lane & 15, g = lane >> 4;
    const int m0 = blockIdx.y * 128, n0 = blockIdx.x * 128;
    const int sr = lane >> 3, sc = (lane & 7) * 8;   // staging row/col within 8-row chunk
    const u16* aS = Ab + (size_t)(m0 + sr) * K + sc;
    const u16* bS = Bt + (size_t)(n0 + sr) * K + sc;
    f32x4 acc[4][4] = {};

    // prologue: stage K-tile 0 into buf 0
#pragma unroll
    for (int i = 0; i < 4; ++i) {
        int row = 32 * w + 8 * i;
        gload16(aS + (size_t)row * K, &As[0][row * 64]);
        gload16(bS + (size_t)row * K, &Bs[0][row * 64]);
    }
    __syncthreads();

    int buf = 0;
    for (int kt = 0; kt < 16; ++kt) {
        // issue next K-tile's DMA into the other buffer (lands under compute)
        if (kt < 15) {
            const int k1 = (kt + 1) * 64;
#pragma unroll
            for (int i = 0; i < 4; ++i) {
                int row = 32 * w + 8 * i;
                gload16(aS + (size_t)row * K + k1, &As[buf ^ 1][row * 64]);
                gload16(bS + (size_t)row * K + k1, &Bs[buf ^ 1][row * 64]);
            }
        }
        // compute current buffer
#pragma unroll
        for (int kk = 0; kk < 2; ++kk) {
            bf16x8 af[4], bfr[4];
#pragma unroll
            for (int m = 0; m < 4; ++m)
                af[m] = *(const bf16x8*)&As[buf][(wr * 64 + m * 16 + c) * 64 + kk * 32 + 8 * g];
#pragma unroll
            for (int n = 0; n < 4; ++n)
                bfr[n] = *(const bf16x8*)&Bs[buf][(wc * 64 + n * 16 + c) * 64 + kk * 32 + 8 * g];
#pragma unroll
            for (int m = 0; m < 4; ++m)
#pragma unroll
                for (int n = 0; n < 4; ++n)
                    acc[m][n] = __builtin_amdgcn_mfma_f32_16x16x32_bf16(af[m], bfr[n], acc[m][n], 0, 0, 0);
        }
        __syncthreads();   // drain next-tile DMA + fence reads of current buf
        buf ^= 1;
    }
#pragma unroll
    for (int n = 0; n < 4; ++n) {
        int col = n0 + wc * 64 + n * 16 + c;
        float bv = BIAS ? bias[col] : 0.0f;
#pragma unroll
        for (int m = 0; m < 4; ++m) {
            int row0 = m0 + wr * 64 + m * 16 + 4 * g;
#pragma unroll
            for (int r = 0; r < 4; ++r) {
                if (BIAS) Cf[(row0 + r) * 1024 + col] = acc[m][n][r] + bv;
                else      Cb[(row0 + r) * 1024 + col] = f2b(acc[m][n][r]);
            }
        }
    }
}

// ---------------- LayerNorm over D=1024 (bf16 in), write bf16 [bh][s][hd] -------
__global__ __launch_bounds__(256)
void ln_kernel(const u16* __restrict__ P, const float* __restrict__ gamma,
               const float* __restrict__ beta, float mul, u16* __restrict__ Out) {
    const int row = blockIdx.x;
    const int tid = threadIdx.x;
    const int lane = tid & 63, w = tid >> 6;
    u16x4 xr = *(const u16x4*)(P + row * 1024 + tid * 4);
    float x0 = bf2f(xr[0]), x1 = bf2f(xr[1]), x2 = bf2f(xr[2]), x3 = bf2f(xr[3]);
    float s = x0 + x1 + x2 + x3;
    float sq = x0 * x0 + x1 * x1 + x2 * x2 + x3 * x3;
#pragma unroll
    for (int m = 1; m < 64; m <<= 1) { s += __shfl_xor(s, m); sq += __shfl_xor(sq, m); }
    __shared__ float red[8];
    if (lane == 0) { red[w] = s; red[4 + w] = sq; }
    __syncthreads();
    float st = red[0] + red[1] + red[2] + red[3];
    float sqt = red[4] + red[5] + red[6] + red[7];
    float mu = st * (1.0f / 1024.0f);
    float var = sqt * (1.0f / 1024.0f) - mu * mu;
    float rs = rsqrtf(var + 1e-5f);
    f32x4 gm = *(const f32x4*)(gamma + tid * 4);
    f32x4 bt = *(const f32x4*)(beta + tid * 4);
    float xs[4] = {x0, x1, x2, x3};
    u16x4 pk;
#pragma unroll
    for (int j = 0; j < 4; ++j)
        pk[j] = f2b(((xs[j] - mu) * rs * gm[j] + bt[j]) * mul);
    const int b = row >> 11, sI = row & 2047;
    const int col = tid * 4, hh = col >> 6, d = col & 63;
    *(u16x4*)(Out + (((b * 16 + hh) * 2048 + sI) << 6) + d) = pk;
}

// ---------------- V transpose: Vt[bh][64][S] (bf16 in/out) ----------------------
__global__ __launch_bounds__(256)
void vt_kernel(const u16* __restrict__ P, u16* __restrict__ Vt) {
    __shared__ u16 T[64][72];
    const int t = threadIdx.x;
    const int bh = blockIdx.y, s0 = blockIdx.x * 64;
    const int b = bh >> 4, h = bh & 15;
#pragma unroll
    for (int e = 0; e < 4; ++e) {
        int row = e * 16 + (t >> 4), c4 = (t & 15) * 4;
        u16x4 v = *(const u16x4*)(P + (b * 2048 + s0 + row) * 1024 + h * 64 + c4);
        *(u16x4*)&T[row][c4] = v;
    }
    __syncthreads();
#pragma unroll
    for (int e = 0; e < 4; ++e) {
        int dd = e * 16 + (t >> 4), s4 = (t & 15) * 4;
        u16x4 pk = { T[s4][dd], T[s4 + 1][dd], T[s4 + 2][dd], T[s4 + 3][dd] };
        *(u16x4*)(Vt + ((size_t)bh * 64 + dd) * 2048 + s0 + s4) = pk;
    }
}

// ---------------- flash attention v5 (round-7 exact): no-max softmax ------------
__global__ __launch_bounds__(256)
void attn_kernel(const u16* __restrict__ Qa, const u16* __restrict__ Ka,
                 const u16* __restrict__ Vt, u16* __restrict__ Xa) {
    __shared__ u16 Ks[2][4096];   // 8KB each: [64][64] swizzled
    __shared__ u16 Vs[2][4096];   // 8KB each: [64][64] swizzled (rows = d)
    __shared__ u16 Pl[4][1024];   // 2KB/wave: [16 q][64 k] swizzled
    const int tid = threadIdx.x;
    const int lane = tid & 63, w = tid >> 6;
    const int c = lane & 15, g = lane >> 4;
    const int bid = blockIdx.x;
    const int bh = (bid & 7) * 8 + ((bid >> 3) & 7);
    const int q0 = (bid >> 6) * 64;
    const int b = bh >> 4, h = bh & 15;

    const int qrow = q0 + w * 16 + c;
    const u16* qptr = Qa + ((size_t)bh * 2048 + qrow) * 64;
    bf16x8 qf0 = *(const bf16x8*)(qptr + 8 * g);
    bf16x8 qf1 = *(const bf16x8*)(qptr + 32 + 8 * g);

    const int sr = lane >> 3;
    const int scg = ((lane & 7) ^ sr) * 8;
    const u16* kA = Ka + ((size_t)bh * 2048 + sr) * 64 + scg;
    const u16* vA = Vt + ((size_t)bh * 64 + sr) * 2048 + scg;
    const int pswz = (c & 7) << 4;

    f32x4 o[4] = {};
    float li = 0.f;
    char* pb = (char*)&Pl[w][0];

    // prologue: stage tile 0 into buf 0
#pragma unroll
    for (int j = 0; j < 2; ++j) {
        const int m = 2 * w + j;
        gload16(kA + (size_t)(8 * m) * 64, &Ks[0][8 * m * 64]);
        gload16(vA + (size_t)(8 * m) * 2048, &Vs[0][8 * m * 64]);
    }
    __syncthreads();

    int cur = 0;
    for (int t = 0; t < 32; ++t) {
        // issue async staging of next tile into the other buffer
        const int tn = (t + 1) & 31;
#pragma unroll
        for (int j = 0; j < 2; ++j) {
            const int m = 2 * w + j;
            gload16(kA + (size_t)(tn * 64 + 8 * m) * 64, &Ks[cur ^ 1][8 * m * 64]);
            gload16(vA + (size_t)(8 * m) * 2048 + tn * 64, &Vs[cur ^ 1][8 * m * 64]);
        }

        // QK^T (swapped): sacc[ct][r] = S[k=16ct+4g+r][q=c]
        const char* kbase = (const char*)&Ks[cur][0];
        f32x4 sacc[4] = {};
        __builtin_amdgcn_s_setprio(1);
#pragma unroll
        for (int ct = 0; ct < 4; ++ct) {
            const int rb = (c + 16 * ct) * 128;
            bf16x8 kf0 = *(const bf16x8*)(kbase + rb + ((16 * g) ^ pswz));
            bf16x8 kf1 = *(const bf16x8*)(kbase + rb + ((64 + 16 * g) ^ pswz));
            sacc[ct] = __builtin_amdgcn_mfma_f32_16x16x32_bf16(kf0, qf0, sacc[ct], 0, 0, 0);
            sacc[ct] = __builtin_amdgcn_mfma_f32_16x16x32_bf16(kf1, qf1, sacc[ct], 0, 0, 0);
        }
        __builtin_amdgcn_s_setprio(0);

        // P = exp2(S) directly (no max shift); lane-partial sum into li
#pragma unroll
        for (int ct = 0; ct < 4; ++ct) {
            float e0 = exp2f(sacc[ct][0]);
            float e1 = exp2f(sacc[ct][1]);
            float e2 = exp2f(sacc[ct][2]);
            float e3 = exp2f(sacc[ct][3]);
            li += (e0 + e1) + (e2 + e3);
            u16x4 pk = { f2b(e0), f2b(e1), f2b(e2), f2b(e3) };
            *(u16x4*)(pb + 128 * c + ((32 * ct + 8 * g) ^ pswz)) = pk;
        }

        // PV from Pl (wave-private) and Vs[cur]
        const char* vb = (const char*)&Vs[cur][0];
        __builtin_amdgcn_s_setprio(1);
#pragma unroll
        for (int s4 = 0; s4 < 2; ++s4) {
            const int co = ((64 * s4 + 16 * g) ^ pswz);
            bf16x8 af = *(const bf16x8*)(pb + 128 * c + co);
#pragma unroll
            for (int n = 0; n < 4; ++n) {
                bf16x8 vf = *(const bf16x8*)(vb + (c + 16 * n) * 128 + co);
                o[n] = __builtin_amdgcn_mfma_f32_16x16x32_bf16(af, vf, o[n], 0, 0, 0);
            }
        }
        __builtin_amdgcn_s_setprio(0);

        __syncthreads();   // next tile staged + all reads of cur done
        cur ^= 1;
    }

    // reduce li across the 4 g-groups once, then normalize
    li += __shfl_xor(li, 16);
    li += __shfl_xor(li, 32);
    float inv = 1.0f / li;
    float i0 = __shfl(inv, 4 * g + 0);
    float i1 = __shfl(inv, 4 * g + 1);
    float i2 = __shfl(inv, 4 * g + 2);
    float i3 = __shfl(inv, 4 * g + 3);
    float iv[4] = {i0, i1, i2, i3};
#pragma unroll
    for (int r = 0; r < 4; ++r) {
        int row = q0 + w * 16 + 4 * g + r;
        u16* xp = Xa + ((size_t)b * 2048 + row) * 1024 + h * 64;
#pragma unroll
        for (int n = 0; n < 4; ++n)
            xp[n * 16 + c] = f2b(o[n][r] * iv[r]);
    }
}

// ---------------- launch --------------------------------------------------------
extern "C" void kernel_launch(void* const* d_in, const int* in_sizes, int n_in,
                              void* d_out, int out_size, void* d_ws, size_t ws_size,
                              hipStream_t stream) {
    const float* q   = (const float*)d_in[0];
    const float* k   = (const float*)d_in[1];
    const float* v   = (const float*)d_in[2];
    const float* Wq  = (const float*)d_in[3];
    const float* Wk  = (const float*)d_in[4];
    const float* Wv  = (const float*)d_in[5];
    const float* Wo  = (const float*)d_in[6];
    const float* bo  = (const float*)d_in[7];
    const float* qg  = (const float*)d_in[8];
    const float* qbt = (const float*)d_in[9];
    const float* kg  = (const float*)d_in[10];
    const float* kbt = (const float*)d_in[11];

    char* ws = (char*)d_ws;
    u16* Wt = (u16*)(ws);                    //  8,388,608 B
    u16* Pb = (u16*)(ws + 8388608);          // 16,777,216 B
    u16* Qa = (u16*)(ws + 25165824);         // 16,777,216 B
    u16* Ka = (u16*)(ws + 41943040);         // 16,777,216 B
    u16* Vt = (u16*)(ws + 58720256);         // 16,777,216 B
    u16* Ib = (u16*)(ws + 75497472);         // 16,777,216 B bf16 input slot (end 92MB)
    u16* Xa = Pb;                            // reuse: P dead after vt_kernel

    const float MUL_Q = 0.04508422002778f;   // (1/32) * log2(e)

    wt_kernel<<<dim3(16, 16, 4), 256, 0, stream>>>(Wq, Wk, Wv, Wo, Wt);

    cvt_kernel<<<4096, 256, 0, stream>>>(q, Ib);
    gemm_kernel<0><<<dim3(8, 64), 256, 0, stream>>>(Ib, Wt, Pb, nullptr, nullptr);
    ln_kernel<<<8192, 256, 0, stream>>>(Pb, qg, qbt, MUL_Q, Qa);

    cvt_kernel<<<4096, 256, 0, stream>>>(k, Ib);
    gemm_kernel<0><<<dim3(8, 64), 256, 0, stream>>>(Ib, Wt + 1048576, Pb, nullptr, nullptr);
    ln_kernel<<<8192, 256, 0, stream>>>(Pb, kg, kbt, 1.0f, Ka);

    cvt_kernel<<<4096, 256, 0, stream>>>(v, Ib);
    gemm_kernel<0><<<dim3(8, 64), 256, 0, stream>>>(Ib, Wt + 2097152, Pb, nullptr, nullptr);
    vt_kernel<<<dim3(32, 64), 256, 0, stream>>>(Pb, Vt);

    attn_kernel<<<2048, 256, 0, stream>>>(Qa, Ka, Vt, Xa);

    gemm_kernel<1><<<dim3(8, 64), 256, 0, stream>>>((const u16*)Xa, Wt + 3145728, nullptr, (float*)d_out, bo);
}

// Round 10
// 290.176 us; speedup vs baseline: 1.5608x; 1.1355x over previous
//
#include <hip/hip_runtime.h>
#include <hip/hip_bf16.h>

typedef unsigned short u16;
typedef __attribute__((ext_vector_type(8))) short bf16x8;
typedef __attribute__((ext_vector_type(4))) float f32x4;
typedef __attribute__((ext_vector_type(4))) unsigned short u16x4;
typedef __attribute__((ext_vector_type(4))) unsigned int u32x4;

__device__ __forceinline__ u16 f2b(float f) {
    __hip_bfloat16 h = __float2bfloat16(f);
    u16 r; __builtin_memcpy(&r, &h, 2); return r;
}
__device__ __forceinline__ float bf2f(u16 u) {
    return __uint_as_float(((unsigned)u) << 16);
}
// async global->LDS, 16B per lane; dest = wave-uniform base + lane*16 (HW)
__device__ __forceinline__ void gload16(const void* g, void* l) {
    __builtin_amdgcn_global_load_lds(
        (const __attribute__((address_space(1))) unsigned int*)g,
        (__attribute__((address_space(3))) unsigned int*)l, 16, 0, 0);
}

// ---------------- fp32 -> bf16 bulk convert (8 elems/thread) --------------------
__global__ __launch_bounds__(256)
void cvt_kernel(const float* __restrict__ in, u16* __restrict__ out) {
    size_t i = ((size_t)blockIdx.x * 256 + threadIdx.x) * 8;
    f32x4 a = *(const f32x4*)(in + i);
    f32x4 b = *(const f32x4*)(in + i + 4);
    u16x4 p0 = { f2b(a[0]), f2b(a[1]), f2b(a[2]), f2b(a[3]) };
    u16x4 p1 = { f2b(b[0]), f2b(b[1]), f2b(b[2]), f2b(b[3]) };
    *(u16x4*)(out + i) = p0;
    *(u16x4*)(out + i + 4) = p1;
}

// ---------------- weight transpose + convert: Wt[n][k] = bf16(W[k][n]) ----------
__global__ __launch_bounds__(256)
void wt_kernel(const float* __restrict__ Wq, const float* __restrict__ Wk,
               const float* __restrict__ Wv, const float* __restrict__ Wo,
               u16* __restrict__ Wt) {
    const float* W = blockIdx.z == 0 ? Wq : blockIdx.z == 1 ? Wk : blockIdx.z == 2 ? Wv : Wo;
    u16* Out = Wt + (size_t)blockIdx.z * (1024 * 1024);
    __shared__ float T[64][65];
    const int t = threadIdx.x;
    const int r0 = blockIdx.y * 64, c0 = blockIdx.x * 64;
#pragma unroll
    for (int e = 0; e < 4; ++e) {
        int row = e * 16 + (t >> 4), c4 = (t & 15) * 4;
        f32x4 v = *(const f32x4*)(W + (r0 + row) * 1024 + c0 + c4);
        T[row][c4] = v[0]; T[row][c4 + 1] = v[1]; T[row][c4 + 2] = v[2]; T[row][c4 + 3] = v[3];
    }
    __syncthreads();
#pragma unroll
    for (int e = 0; e < 4; ++e) {
        int orow = e * 16 + (t >> 4), oc4 = (t & 15) * 4;
        u16x4 pk = { f2b(T[oc4][orow]), f2b(T[oc4 + 1][orow]),
                     f2b(T[oc4 + 2][orow]), f2b(T[oc4 + 3][orow]) };
        *(u16x4*)(Out + (c0 + orow) * 1024 + r0 + oc4) = pk;
    }
}

// ---------------- GEMM (round-7 proven): single-buffer LDS, gload16 DMA ---------
template <int BIAS>
__global__ __launch_bounds__(256)
void gemm_kernel(const u16* __restrict__ Ab, const u16* __restrict__ Bt,
                 u16* __restrict__ Cb, float* __restrict__ Cf,
                 const float* __restrict__ bias) {
    constexpr int K = 1024;
    __shared__ u16 As[128 * 64];
    __shared__ u16 Bs[128 * 64];
    const int tid = threadIdx.x;
    const int lane = tid & 63, w = tid >> 6;
    const int wr = w >> 1, wc = w & 1;
    const int c = lane & 15, g = lane >> 4;
    const int m0 = blockIdx.y * 128, n0 = blockIdx.x * 128;
    const int sr = lane >> 3, sc = (lane & 7) * 8;   // staging row/col for gload
    f32x4 acc[4][4] = {};
    for (int kt = 0; kt < 16; ++kt) {
        const int k0 = kt * 64;
#pragma unroll
        for (int i = 0; i < 4; ++i) {
            int row = 32 * w + 8 * i;
            gload16(Ab + (size_t)(m0 + row + sr) * K + k0 + sc, &As[row * 64]);
            gload16(Bt + (size_t)(n0 + row + sr) * K + k0 + sc, &Bs[row * 64]);
        }
        __syncthreads();
#pragma unroll
        for (int kk = 0; kk < 2; ++kk) {
            bf16x8 af[4], bfr[4];
#pragma unroll
            for (int m = 0; m < 4; ++m)
                af[m] = *(const bf16x8*)&As[(wr * 64 + m * 16 + c) * 64 + kk * 32 + 8 * g];
#pragma unroll
            for (int n = 0; n < 4; ++n)
                bfr[n] = *(const bf16x8*)&Bs[(wc * 64 + n * 16 + c) * 64 + kk * 32 + 8 * g];
#pragma unroll
            for (int m = 0; m < 4; ++m)
#pragma unroll
                for (int n = 0; n < 4; ++n)
                    acc[m][n] = __builtin_amdgcn_mfma_f32_16x16x32_bf16(af[m], bfr[n], acc[m][n], 0, 0, 0);
        }
        __syncthreads();
    }
#pragma unroll
    for (int n = 0; n < 4; ++n) {
        int col = n0 + wc * 64 + n * 16 + c;
        float bv = BIAS ? bias[col] : 0.0f;
#pragma unroll
        for (int m = 0; m < 4; ++m) {
            int row0 = m0 + wr * 64 + m * 16 + 4 * g;
#pragma unroll
            for (int r = 0; r < 4; ++r) {
                if (BIAS) Cf[(row0 + r) * 1024 + col] = acc[m][n][r] + bv;
                else      Cb[(row0 + r) * 1024 + col] = f2b(acc[m][n][r]);
            }
        }
    }
}

// ---------------- LayerNorm over D=1024 (bf16 in), write bf16 [bh][s][hd] -------
__global__ __launch_bounds__(256)
void ln_kernel(const u16* __restrict__ P, const float* __restrict__ gamma,
               const float* __restrict__ beta, float mul, u16* __restrict__ Out) {
    const int row = blockIdx.x;
    const int tid = threadIdx.x;
    const int lane = tid & 63, w = tid >> 6;
    u16x4 xr = *(const u16x4*)(P + row * 1024 + tid * 4);
    float x0 = bf2f(xr[0]), x1 = bf2f(xr[1]), x2 = bf2f(xr[2]), x3 = bf2f(xr[3]);
    float s = x0 + x1 + x2 + x3;
    float sq = x0 * x0 + x1 * x1 + x2 * x2 + x3 * x3;
#pragma unroll
    for (int m = 1; m < 64; m <<= 1) { s += __shfl_xor(s, m); sq += __shfl_xor(sq, m); }
    __shared__ float red[8];
    if (lane == 0) { red[w] = s; red[4 + w] = sq; }
    __syncthreads();
    float st = red[0] + red[1] + red[2] + red[3];
    float sqt = red[4] + red[5] + red[6] + red[7];
    float mu = st * (1.0f / 1024.0f);
    float var = sqt * (1.0f / 1024.0f) - mu * mu;
    float rs = rsqrtf(var + 1e-5f);
    f32x4 gm = *(const f32x4*)(gamma + tid * 4);
    f32x4 bt = *(const f32x4*)(beta + tid * 4);
    float xs[4] = {x0, x1, x2, x3};
    u16x4 pk;
#pragma unroll
    for (int j = 0; j < 4; ++j)
        pk[j] = f2b(((xs[j] - mu) * rs * gm[j] + bt[j]) * mul);
    const int b = row >> 11, sI = row & 2047;
    const int col = tid * 4, hh = col >> 6, d = col & 63;
    *(u16x4*)(Out + (((b * 16 + hh) * 2048 + sI) << 6) + d) = pk;
}

// ---------------- V transpose: Vt[bh][64][S] (bf16 in/out) ----------------------
__global__ __launch_bounds__(256)
void vt_kernel(const u16* __restrict__ P, u16* __restrict__ Vt) {
    __shared__ u16 T[64][72];
    const int t = threadIdx.x;
    const int bh = blockIdx.y, s0 = blockIdx.x * 64;
    const int b = bh >> 4, h = bh & 15;
#pragma unroll
    for (int e = 0; e < 4; ++e) {
        int row = e * 16 + (t >> 4), c4 = (t & 15) * 4;
        u16x4 v = *(const u16x4*)(P + (b * 2048 + s0 + row) * 1024 + h * 64 + c4);
        *(u16x4*)&T[row][c4] = v;
    }
    __syncthreads();
#pragma unroll
    for (int e = 0; e < 4; ++e) {
        int dd = e * 16 + (t >> 4), s4 = (t & 15) * 4;
        u16x4 pk = { T[s4][dd], T[s4 + 1][dd], T[s4 + 2][dd], T[s4 + 3][dd] };
        *(u16x4*)(Vt + ((size_t)bh * 64 + dd) * 2048 + s0 + s4) = pk;
    }
}

// ---------------- flash attention v6: no-max softmax + MFMA row-sum -------------
// li computed on the MFMA pipe: o4 = mfma(P_frag, ones) accumulates sum_k P[k][q]
// in the same row layout as o[n] -- zero shuffles, no VALU adds.
__global__ __launch_bounds__(256)
void attn_kernel(const u16* __restrict__ Qa, const u16* __restrict__ Ka,
                 const u16* __restrict__ Vt, u16* __restrict__ Xa) {
    __shared__ u16 Ks[2][4096];   // 8KB each: [64][64] swizzled
    __shared__ u16 Vs[2][4096];   // 8KB each: [64][64] swizzled (rows = d)
    __shared__ u16 Pl[4][1024];   // 2KB/wave: [16 q][64 k] swizzled
    const int tid = threadIdx.x;
    const int lane = tid & 63, w = tid >> 6;
    const int c = lane & 15, g = lane >> 4;
    const int bid = blockIdx.x;
    const int bh = (bid & 7) * 8 + ((bid >> 3) & 7);
    const int q0 = (bid >> 6) * 64;
    const int b = bh >> 4, h = bh & 15;

    const int qrow = q0 + w * 16 + c;
    const u16* qptr = Qa + ((size_t)bh * 2048 + qrow) * 64;
    bf16x8 qf0 = *(const bf16x8*)(qptr + 8 * g);
    bf16x8 qf1 = *(const bf16x8*)(qptr + 32 + 8 * g);

    const int sr = lane >> 3;
    const int scg = ((lane & 7) ^ sr) * 8;
    const u16* kA = Ka + ((size_t)bh * 2048 + sr) * 64 + scg;
    const u16* vA = Vt + ((size_t)bh * 64 + sr) * 2048 + scg;
    const int pswz = (c & 7) << 4;

    // B-fragment of all-ones (bf16 1.0 = 0x3F80) for the row-sum MFMA
    bf16x8 vones;
#pragma unroll
    for (int j = 0; j < 8; ++j) vones[j] = (short)0x3F80;

    f32x4 o[4] = {};
    f32x4 o4 = {};                 // row-sum accumulator (li per output row)
    char* pb = (char*)&Pl[w][0];

    // prologue: stage tile 0 into buf 0
#pragma unroll
    for (int j = 0; j < 2; ++j) {
        const int m = 2 * w + j;
        gload16(kA + (size_t)(8 * m) * 64, &Ks[0][8 * m * 64]);
        gload16(vA + (size_t)(8 * m) * 2048, &Vs[0][8 * m * 64]);
    }
    __syncthreads();

    int cur = 0;
    for (int t = 0; t < 32; ++t) {
        // issue async staging of next tile into the other buffer
        const int tn = (t + 1) & 31;
#pragma unroll
        for (int j = 0; j < 2; ++j) {
            const int m = 2 * w + j;
            gload16(kA + (size_t)(tn * 64 + 8 * m) * 64, &Ks[cur ^ 1][8 * m * 64]);
            gload16(vA + (size_t)(8 * m) * 2048 + tn * 64, &Vs[cur ^ 1][8 * m * 64]);
        }

        // QK^T (swapped): sacc[ct][r] = S[k=16ct+4g+r][q=c]
        const char* kbase = (const char*)&Ks[cur][0];
        f32x4 sacc[4] = {};
        __builtin_amdgcn_s_setprio(1);
#pragma unroll
        for (int ct = 0; ct < 4; ++ct) {
            const int rb = (c + 16 * ct) * 128;
            bf16x8 kf0 = *(const bf16x8*)(kbase + rb + ((16 * g) ^ pswz));
            bf16x8 kf1 = *(const bf16x8*)(kbase + rb + ((64 + 16 * g) ^ pswz));
            sacc[ct] = __builtin_amdgcn_mfma_f32_16x16x32_bf16(kf0, qf0, sacc[ct], 0, 0, 0);
            sacc[ct] = __builtin_amdgcn_mfma_f32_16x16x32_bf16(kf1, qf1, sacc[ct], 0, 0, 0);
        }
        __builtin_amdgcn_s_setprio(0);

        // P = exp2(S) directly (no max shift; LN'd inputs keep |S| small)
#pragma unroll
        for (int ct = 0; ct < 4; ++ct) {
            float e0 = exp2f(sacc[ct][0]);
            float e1 = exp2f(sacc[ct][1]);
            float e2 = exp2f(sacc[ct][2]);
            float e3 = exp2f(sacc[ct][3]);
            u16x4 pk = { f2b(e0), f2b(e1), f2b(e2), f2b(e3) };
            *(u16x4*)(pb + 128 * c + ((32 * ct + 8 * g) ^ pswz)) = pk;
        }

        // PV from Pl (wave-private) and Vs[cur]; o4 += P*ones = row-sum
        const char* vb = (const char*)&Vs[cur][0];
        __builtin_amdgcn_s_setprio(1);
#pragma unroll
        for (int s4 = 0; s4 < 2; ++s4) {
            const int co = ((64 * s4 + 16 * g) ^ pswz);
            bf16x8 af = *(const bf16x8*)(pb + 128 * c + co);
#pragma unroll
            for (int n = 0; n < 4; ++n) {
                bf16x8 vf = *(const bf16x8*)(vb + (c + 16 * n) * 128 + co);
                o[n] = __builtin_amdgcn_mfma_f32_16x16x32_bf16(af, vf, o[n], 0, 0, 0);
            }
            o4 = __builtin_amdgcn_mfma_f32_16x16x32_bf16(af, vones, o4, 0, 0, 0);
        }
        __builtin_amdgcn_s_setprio(0);

        __syncthreads();   // next tile staged + all reads of cur done
        cur ^= 1;
    }

    // o4[r] = li for output row 4g+r (all cols identical) -- no shuffles needed
    float iv[4] = { 1.0f / o4[0], 1.0f / o4[1], 1.0f / o4[2], 1.0f / o4[3] };
#pragma unroll
    for (int r = 0; r < 4; ++r) {
        int row = q0 + w * 16 + 4 * g + r;
        u16* xp = Xa + ((size_t)b * 2048 + row) * 1024 + h * 64;
#pragma unroll
        for (int n = 0; n < 4; ++n)
            xp[n * 16 + c] = f2b(o[n][r] * iv[r]);
    }
}

// ---------------- launch --------------------------------------------------------
extern "C" void kernel_launch(void* const* d_in, const int* in_sizes, int n_in,
                              void* d_out, int out_size, void* d_ws, size_t ws_size,
                              hipStream_t stream) {
    const float* q   = (const float*)d_in[0];
    const float* k   = (const float*)d_in[1];
    const float* v   = (const float*)d_in[2];
    const float* Wq  = (const float*)d_in[3];
    const float* Wk  = (const float*)d_in[4];
    const float* Wv  = (const float*)d_in[5];
    const float* Wo  = (const float*)d_in[6];
    const float* bo  = (const float*)d_in[7];
    const float* qg  = (const float*)d_in[8];
    const float* qbt = (const float*)d_in[9];
    const float* kg  = (const float*)d_in[10];
    const float* kbt = (const float*)d_in[11];

    char* ws = (char*)d_ws;
    u16* Wt = (u16*)(ws);                    //  8,388,608 B
    u16* Pb = (u16*)(ws + 8388608);          // 16,777,216 B
    u16* Qa = (u16*)(ws + 25165824);         // 16,777,216 B
    u16* Ka = (u16*)(ws + 41943040);         // 16,777,216 B
    u16* Vt = (u16*)(ws + 58720256);         // 16,777,216 B
    u16* Ib = (u16*)(ws + 75497472);         // 16,777,216 B bf16 input slot (end 92MB)
    u16* Xa = Pb;                            // reuse: P dead after vt_kernel

    const float MUL_Q = 0.04508422002778f;   // (1/32) * log2(e)

    wt_kernel<<<dim3(16, 16, 4), 256, 0, stream>>>(Wq, Wk, Wv, Wo, Wt);

    cvt_kernel<<<4096, 256, 0, stream>>>(q, Ib);
    gemm_kernel<0><<<dim3(8, 64), 256, 0, stream>>>(Ib, Wt, Pb, nullptr, nullptr);
    ln_kernel<<<8192, 256, 0, stream>>>(Pb, qg, qbt, MUL_Q, Qa);

    cvt_kernel<<<4096, 256, 0, stream>>>(k, Ib);
    gemm_kernel<0><<<dim3(8, 64), 256, 0, stream>>>(Ib, Wt + 1048576, Pb, nullptr, nullptr);
    ln_kernel<<<8192, 256, 0, stream>>>(Pb, kg, kbt, 1.0f, Ka);

    cvt_kernel<<<4096, 256, 0, stream>>>(v, Ib);
    gemm_kernel<0><<<dim3(8, 64), 256, 0, stream>>>(Ib, Wt + 2097152, Pb, nullptr, nullptr);
    vt_kernel<<<dim3(32, 64), 256, 0, stream>>>(Pb, Vt);

    attn_kernel<<<2048, 256, 0, stream>>>(Qa, Ka, Vt, Xa);

    gemm_kernel<1><<<dim3(8, 64), 256, 0, stream>>>((const u16*)Xa, Wt + 3145728, nullptr, (float*)d_out, bo);
}

// Round 11
// 271.414 us; speedup vs baseline: 1.6687x; 1.0691x over previous
//
#include <hip/hip_runtime.h>
#include <hip/hip_bf16.h>

typedef unsigned short u16;
typedef __attribute__((ext_vector_type(8))) short bf16x8;
typedef __attribute__((ext_vector_type(4))) float f32x4;
typedef __attribute__((ext_vector_type(16))) float f32x16;
typedef __attribute__((ext_vector_type(4))) unsigned short u16x4;
typedef __attribute__((ext_vector_type(4))) unsigned int u32x4;
typedef __attribute__((ext_vector_type(2))) int i32x2;

__device__ __forceinline__ u16 f2b(float f) {
    __hip_bfloat16 h = __float2bfloat16(f);
    u16 r; __builtin_memcpy(&r, &h, 2); return r;
}
__device__ __forceinline__ float bf2f(u16 u) {
    return __uint_as_float(((unsigned)u) << 16);
}
// async global->LDS, 16B per lane; dest = wave-uniform base + lane*16 (HW)
__device__ __forceinline__ void gload16(const void* g, void* l) {
    __builtin_amdgcn_global_load_lds(
        (const __attribute__((address_space(1))) unsigned int*)g,
        (__attribute__((address_space(3))) unsigned int*)l, 16, 0, 0);
}
// pack 2 f32 -> u32 of 2 bf16 (RNE), single HW instr
__device__ __forceinline__ unsigned cvtpk(float lo, float hi) {
    unsigned d;
    asm("v_cvt_pk_bf16_f32 %0, %1, %2" : "=v"(d) : "v"(lo), "v"(hi));
    return d;
}
// build PV A-fragment (8 bf16) from own 8 P-values via cvt_pk + permlane32_swap.
// a0..a3 = P at m2=2*s2 (k=8m2+4h+r2), b0..b3 = P at m2=2*s2+1.
__device__ __forceinline__ bf16x8 mk_pa(float a0, float a1, float a2, float a3,
                                        float b0, float b1, float b2, float b3) {
    int A0 = (int)cvtpk(a0, a1), A1 = (int)cvtpk(a2, a3);
    int B0 = (int)cvtpk(b0, b1), B1 = (int)cvtpk(b2, b3);
    i32x2 r0 = __builtin_amdgcn_permlane32_swap(A0, B0, false, false);
    i32x2 r1 = __builtin_amdgcn_permlane32_swap(A1, B1, false, false);
    u32x4 fw = { (unsigned)r0[0], (unsigned)r1[0], (unsigned)r0[1], (unsigned)r1[1] };
    return __builtin_bit_cast(bf16x8, fw);
}

// ---------------- fp32 -> bf16 bulk convert (8 elems/thread) --------------------
__global__ __launch_bounds__(256)
void cvt_kernel(const float* __restrict__ in, u16* __restrict__ out) {
    size_t i = ((size_t)blockIdx.x * 256 + threadIdx.x) * 8;
    f32x4 a = *(const f32x4*)(in + i);
    f32x4 b = *(const f32x4*)(in + i + 4);
    u16x4 p0 = { f2b(a[0]), f2b(a[1]), f2b(a[2]), f2b(a[3]) };
    u16x4 p1 = { f2b(b[0]), f2b(b[1]), f2b(b[2]), f2b(b[3]) };
    *(u16x4*)(out + i) = p0;
    *(u16x4*)(out + i + 4) = p1;
}

// ---------------- weight transpose + convert: Wt[n][k] = bf16(W[k][n]) ----------
__global__ __launch_bounds__(256)
void wt_kernel(const float* __restrict__ Wq, const float* __restrict__ Wk,
               const float* __restrict__ Wv, const float* __restrict__ Wo,
               u16* __restrict__ Wt) {
    const float* W = blockIdx.z == 0 ? Wq : blockIdx.z == 1 ? Wk : blockIdx.z == 2 ? Wv : Wo;
    u16* Out = Wt + (size_t)blockIdx.z * (1024 * 1024);
    __shared__ float T[64][65];
    const int t = threadIdx.x;
    const int r0 = blockIdx.y * 64, c0 = blockIdx.x * 64;
#pragma unroll
    for (int e = 0; e < 4; ++e) {
        int row = e * 16 + (t >> 4), c4 = (t & 15) * 4;
        f32x4 v = *(const f32x4*)(W + (r0 + row) * 1024 + c0 + c4);
        T[row][c4] = v[0]; T[row][c4 + 1] = v[1]; T[row][c4 + 2] = v[2]; T[row][c4 + 3] = v[3];
    }
    __syncthreads();
#pragma unroll
    for (int e = 0; e < 4; ++e) {
        int orow = e * 16 + (t >> 4), oc4 = (t & 15) * 4;
        u16x4 pk = { f2b(T[oc4][orow]), f2b(T[oc4 + 1][orow]),
                     f2b(T[oc4 + 2][orow]), f2b(T[oc4 + 3][orow]) };
        *(u16x4*)(Out + (c0 + orow) * 1024 + r0 + oc4) = pk;
    }
}

// ---------------- GEMM (round-7 proven): single-buffer LDS, gload16 DMA ---------
template <int BIAS>
__global__ __launch_bounds__(256)
void gemm_kernel(const u16* __restrict__ Ab, const u16* __restrict__ Bt,
                 u16* __restrict__ Cb, float* __restrict__ Cf,
                 const float* __restrict__ bias) {
    constexpr int K = 1024;
    __shared__ u16 As[128 * 64];
    __shared__ u16 Bs[128 * 64];
    const int tid = threadIdx.x;
    const int lane = tid & 63, w = tid >> 6;
    const int wr = w >> 1, wc = w & 1;
    const int c = lane & 15, g = lane >> 4;
    const int m0 = blockIdx.y * 128, n0 = blockIdx.x * 128;
    const int sr = lane >> 3, sc = (lane & 7) * 8;
    f32x4 acc[4][4] = {};
    for (int kt = 0; kt < 16; ++kt) {
        const int k0 = kt * 64;
#pragma unroll
        for (int i = 0; i < 4; ++i) {
            int row = 32 * w + 8 * i;
            gload16(Ab + (size_t)(m0 + row + sr) * K + k0 + sc, &As[row * 64]);
            gload16(Bt + (size_t)(n0 + row + sr) * K + k0 + sc, &Bs[row * 64]);
        }
        __syncthreads();
#pragma unroll
        for (int kk = 0; kk < 2; ++kk) {
            bf16x8 af[4], bfr[4];
#pragma unroll
            for (int m = 0; m < 4; ++m)
                af[m] = *(const bf16x8*)&As[(wr * 64 + m * 16 + c) * 64 + kk * 32 + 8 * g];
#pragma unroll
            for (int n = 0; n < 4; ++n)
                bfr[n] = *(const bf16x8*)&Bs[(wc * 64 + n * 16 + c) * 64 + kk * 32 + 8 * g];
#pragma unroll
            for (int m = 0; m < 4; ++m)
#pragma unroll
                for (int n = 0; n < 4; ++n)
                    acc[m][n] = __builtin_amdgcn_mfma_f32_16x16x32_bf16(af[m], bfr[n], acc[m][n], 0, 0, 0);
        }
        __syncthreads();
    }
#pragma unroll
    for (int n = 0; n < 4; ++n) {
        int col = n0 + wc * 64 + n * 16 + c;
        float bv = BIAS ? bias[col] : 0.0f;
#pragma unroll
        for (int m = 0; m < 4; ++m) {
            int row0 = m0 + wr * 64 + m * 16 + 4 * g;
#pragma unroll
            for (int r = 0; r < 4; ++r) {
                if (BIAS) Cf[(row0 + r) * 1024 + col] = acc[m][n][r] + bv;
                else      Cb[(row0 + r) * 1024 + col] = f2b(acc[m][n][r]);
            }
        }
    }
}

// ---------------- LayerNorm over D=1024 (bf16 in), write bf16 [bh][s][hd] -------
__global__ __launch_bounds__(256)
void ln_kernel(const u16* __restrict__ P, const float* __restrict__ gamma,
               const float* __restrict__ beta, float mul, u16* __restrict__ Out) {
    const int row = blockIdx.x;
    const int tid = threadIdx.x;
    const int lane = tid & 63, w = tid >> 6;
    u16x4 xr = *(const u16x4*)(P + row * 1024 + tid * 4);
    float x0 = bf2f(xr[0]), x1 = bf2f(xr[1]), x2 = bf2f(xr[2]), x3 = bf2f(xr[3]);
    float s = x0 + x1 + x2 + x3;
    float sq = x0 * x0 + x1 * x1 + x2 * x2 + x3 * x3;
#pragma unroll
    for (int m = 1; m < 64; m <<= 1) { s += __shfl_xor(s, m); sq += __shfl_xor(sq, m); }
    __shared__ float red[8];
    if (lane == 0) { red[w] = s; red[4 + w] = sq; }
    __syncthreads();
    float st = red[0] + red[1] + red[2] + red[3];
    float sqt = red[4] + red[5] + red[6] + red[7];
    float mu = st * (1.0f / 1024.0f);
    float var = sqt * (1.0f / 1024.0f) - mu * mu;
    float rs = rsqrtf(var + 1e-5f);
    f32x4 gm = *(const f32x4*)(gamma + tid * 4);
    f32x4 bt = *(const f32x4*)(beta + tid * 4);
    float xs[4] = {x0, x1, x2, x3};
    u16x4 pk;
#pragma unroll
    for (int j = 0; j < 4; ++j)
        pk[j] = f2b(((xs[j] - mu) * rs * gm[j] + bt[j]) * mul);
    const int b = row >> 11, sI = row & 2047;
    const int col = tid * 4, hh = col >> 6, d = col & 63;
    *(u16x4*)(Out + (((b * 16 + hh) * 2048 + sI) << 6) + d) = pk;
}

// ---------------- V transpose: Vt[bh][64][S] (bf16 in/out) ----------------------
__global__ __launch_bounds__(256)
void vt_kernel(const u16* __restrict__ P, u16* __restrict__ Vt) {
    __shared__ u16 T[64][72];
    const int t = threadIdx.x;
    const int bh = blockIdx.y, s0 = blockIdx.x * 64;
    const int b = bh >> 4, h = bh & 15;
#pragma unroll
    for (int e = 0; e < 4; ++e) {
        int row = e * 16 + (t >> 4), c4 = (t & 15) * 4;
        u16x4 v = *(const u16x4*)(P + (b * 2048 + s0 + row) * 1024 + h * 64 + c4);
        *(u16x4*)&T[row][c4] = v;
    }
    __syncthreads();
#pragma unroll
    for (int e = 0; e < 4; ++e) {
        int dd = e * 16 + (t >> 4), s4 = (t & 15) * 4;
        u16x4 pk = { T[s4][dd], T[s4 + 1][dd], T[s4 + 2][dd], T[s4 + 3][dd] };
        *(u16x4*)(Vt + ((size_t)bh * 64 + dd) * 2048 + s0 + s4) = pk;
    }
}

// ---------------- flash attention v7: 32x32 MFMA, in-register P (T12) -----------
// 4 waves x 32 q-rows (block = 128 q). Swapped QK^T via mfma_32x32x16: lane l
// holds S[k][q=l&31] for 32 k (reg: k=8*(reg>>2)+4*h+(reg&3), h=l>>5).
// P stays in registers: cvt_pk pairs + permlane32_swap build PV A-fragments.
// K/V LDS double-buffered [64][64], XOR-swizzled via pre-swizzled DMA source.
__global__ __launch_bounds__(256, 3)
void attn_kernel(const u16* __restrict__ Qa, const u16* __restrict__ Ka,
                 const u16* __restrict__ Vt, u16* __restrict__ Xa) {
    __shared__ u16 Ks[2][4096];   // 8KB each: [64 k][64 d], row-swizzled
    __shared__ u16 Vs[2][4096];   // 8KB each: [64 d][64 s], row-swizzled
    const int tid = threadIdx.x;
    const int lane = tid & 63, w = tid >> 6;
    const int col = lane & 31, h = lane >> 5;
    const int bid = blockIdx.x;
    const int bh = (bid & 7) * 8 + ((bid >> 3) & 7);
    const int q0 = (bid >> 6) * 128;
    const int b = bh >> 4, hd = bh & 15;
    const int qb = q0 + w * 32;
    const int sw = (col & 7) << 4;   // read-side XOR swizzle (row&7 == col&7)

    // Q fragments (B-operand): qf[s] = Q[qb+col][16s+8h .. +8]
    const u16* qptr = Qa + ((size_t)bh * 2048 + qb + col) * 64;
    bf16x8 qf[4];
#pragma unroll
    for (int s = 0; s < 4; ++s)
        qf[s] = *(const bf16x8*)(qptr + 16 * s + 8 * h);

    // DMA staging geometry (identical to proven v5/v6)
    const int sr = lane >> 3;
    const int scg = ((lane & 7) ^ sr) * 8;
    const u16* kA = Ka + ((size_t)bh * 2048 + sr) * 64 + scg;
    const u16* vA = Vt + ((size_t)bh * 64 + sr) * 2048 + scg;

    f32x16 o0 = {}, o1 = {};
    float li = 0.f;

    // prologue: stage tile 0 into buf 0
#pragma unroll
    for (int j = 0; j < 2; ++j) {
        const int m = 2 * w + j;
        gload16(kA + (size_t)(8 * m) * 64, &Ks[0][8 * m * 64]);
        gload16(vA + (size_t)(8 * m) * 2048, &Vs[0][8 * m * 64]);
    }
    __syncthreads();

    int cur = 0;
    for (int t = 0; t < 32; ++t) {
        const int tn = (t + 1) & 31;
#pragma unroll
        for (int j = 0; j < 2; ++j) {
            const int m = 2 * w + j;
            gload16(kA + (size_t)(tn * 64 + 8 * m) * 64, &Ks[cur ^ 1][8 * m * 64]);
            gload16(vA + (size_t)(8 * m) * 2048 + tn * 64, &Vs[cur ^ 1][8 * m * 64]);
        }

        // QK^T: sacc[kb2] = S^T for k-block [32*kb2, +32), q = qb+col
        const char* kbase = (const char*)&Ks[cur][0];
        f32x16 sacc0 = {}, sacc1 = {};
        __builtin_amdgcn_s_setprio(1);
#pragma unroll
        for (int s = 0; s < 4; ++s) {
            bf16x8 kf0 = *(const bf16x8*)(kbase + (col) * 128       + ((32 * s + 16 * h) ^ sw));
            bf16x8 kf1 = *(const bf16x8*)(kbase + (32 + col) * 128  + ((32 * s + 16 * h) ^ sw));
            sacc0 = __builtin_amdgcn_mfma_f32_32x32x16_bf16(kf0, qf[s], sacc0, 0, 0, 0);
            sacc1 = __builtin_amdgcn_mfma_f32_32x32x16_bf16(kf1, qf[s], sacc1, 0, 0, 0);
        }
        __builtin_amdgcn_s_setprio(0);

        // P = exp2(S) in registers; li accumulates this lane's 32 values
        f32x16 p0, p1;
#pragma unroll
        for (int r = 0; r < 16; ++r) { p0[r] = exp2f(sacc0[r]); }
#pragma unroll
        for (int r = 0; r < 16; ++r) { p1[r] = exp2f(sacc1[r]); }
#pragma unroll
        for (int r = 0; r < 16; ++r) { li += p0[r] + p1[r]; }

        // PV A-fragments fully in-register (cvt_pk + permlane32_swap)
        bf16x8 pa0 = mk_pa(p0[0], p0[1], p0[2], p0[3], p0[4], p0[5], p0[6], p0[7]);
        bf16x8 pa1 = mk_pa(p0[8], p0[9], p0[10], p0[11], p0[12], p0[13], p0[14], p0[15]);
        bf16x8 pa2 = mk_pa(p1[0], p1[1], p1[2], p1[3], p1[4], p1[5], p1[6], p1[7]);
        bf16x8 pa3 = mk_pa(p1[8], p1[9], p1[10], p1[11], p1[12], p1[13], p1[14], p1[15]);

        // PV: o[db] += P^T-frag x V-frag  (V from Vs[d][s] rows)
        const char* vb = (const char*)&Vs[cur][0];
        __builtin_amdgcn_s_setprio(1);
#pragma unroll
        for (int sg = 0; sg < 4; ++sg) {
            bf16x8 pf = sg == 0 ? pa0 : sg == 1 ? pa1 : sg == 2 ? pa2 : pa3;
            const int cb = (32 * sg + 16 * h) ^ sw;
            bf16x8 vf0 = *(const bf16x8*)(vb + (col) * 128      + cb);
            bf16x8 vf1 = *(const bf16x8*)(vb + (32 + col) * 128 + cb);
            o0 = __builtin_amdgcn_mfma_f32_32x32x16_bf16(pf, vf0, o0, 0, 0, 0);
            o1 = __builtin_amdgcn_mfma_f32_32x32x16_bf16(pf, vf1, o1, 0, 0, 0);
        }
        __builtin_amdgcn_s_setprio(0);

        __syncthreads();
        cur ^= 1;
    }

    // li total for q=col (combine lane halves), then per-reg broadcast
    li += __shfl_xor(li, 32);
    float inv = 1.0f / li;
#pragma unroll
    for (int reg = 0; reg < 16; ++reg) {
        const int crow = (reg & 3) + 8 * (reg >> 2) + 4 * h;
        float ivr = __shfl(inv, crow);
        const int row = qb + crow;
        u16* xp = Xa + ((size_t)b * 2048 + row) * 1024 + hd * 64;
        xp[col] = f2b(o0[reg] * ivr);
        xp[32 + col] = f2b(o1[reg] * ivr);
    }
}

// ---------------- launch --------------------------------------------------------
extern "C" void kernel_launch(void* const* d_in, const int* in_sizes, int n_in,
                              void* d_out, int out_size, void* d_ws, size_t ws_size,
                              hipStream_t stream) {
    const float* q   = (const float*)d_in[0];
    const float* k   = (const float*)d_in[1];
    const float* v   = (const float*)d_in[2];
    const float* Wq  = (const float*)d_in[3];
    const float* Wk  = (const float*)d_in[4];
    const float* Wv  = (const float*)d_in[5];
    const float* Wo  = (const float*)d_in[6];
    const float* bo  = (const float*)d_in[7];
    const float* qg  = (const float*)d_in[8];
    const float* qbt = (const float*)d_in[9];
    const float* kg  = (const float*)d_in[10];
    const float* kbt = (const float*)d_in[11];

    char* ws = (char*)d_ws;
    u16* Wt = (u16*)(ws);                    //  8,388,608 B
    u16* Pb = (u16*)(ws + 8388608);          // 16,777,216 B
    u16* Qa = (u16*)(ws + 25165824);         // 16,777,216 B
    u16* Ka = (u16*)(ws + 41943040);         // 16,777,216 B
    u16* Vt = (u16*)(ws + 58720256);         // 16,777,216 B
    u16* Ib = (u16*)(ws + 75497472);         // 16,777,216 B bf16 input slot (end 92MB)
    u16* Xa = Pb;                            // reuse: P dead after vt_kernel

    const float MUL_Q = 0.04508422002778f;   // (1/32) * log2(e)

    wt_kernel<<<dim3(16, 16, 4), 256, 0, stream>>>(Wq, Wk, Wv, Wo, Wt);

    cvt_kernel<<<4096, 256, 0, stream>>>(q, Ib);
    gemm_kernel<0><<<dim3(8, 64), 256, 0, stream>>>(Ib, Wt, Pb, nullptr, nullptr);
    ln_kernel<<<8192, 256, 0, stream>>>(Pb, qg, qbt, MUL_Q, Qa);

    cvt_kernel<<<4096, 256, 0, stream>>>(k, Ib);
    gemm_kernel<0><<<dim3(8, 64), 256, 0, stream>>>(Ib, Wt + 1048576, Pb, nullptr, nullptr);
    ln_kernel<<<8192, 256, 0, stream>>>(Pb, kg, kbt, 1.0f, Ka);

    cvt_kernel<<<4096, 256, 0, stream>>>(v, Ib);
    gemm_kernel<0><<<dim3(8, 64), 256, 0, stream>>>(Ib, Wt + 2097152, Pb, nullptr, nullptr);
    vt_kernel<<<dim3(32, 64), 256, 0, stream>>>(Pb, Vt);

    attn_kernel<<<1024, 256, 0, stream>>>(Qa, Ka, Vt, Xa);

    gemm_kernel<1><<<dim3(8, 64), 256, 0, stream>>>((const u16*)Xa, Wt + 3145728, nullptr, (float*)d_out, bo);
}